// Round 1
// baseline (1739.516 us; speedup 1.0000x reference)
//
#include <hip/hip_runtime.h>

// Problem constants
constexpr int Bn    = 4;
constexpr int Hn    = 192;
constexpr int Wn    = 192;
constexpr int Cn    = 16;     // state channels
constexpr int HIDn  = 128;    // hidden channels
constexpr int HWn   = Hn * Wn;        // 36864
constexpr int BHWn  = Bn * HWn;       // 147456
constexpr int STEPSn = 10;
constexpr int PADn  = 4;
constexpr int KSn   = 9;
constexpr float EPSf  = 1e-5f;
constexpr float FIREf = 0.5f;

// ---------------------------------------------------------------------------
// One-time weight transposes so hot loops read contiguous, wave-uniform rows
//   wtc[tap][c]  = w_p0[c][tap]        (81 x 16)
//   wt1[o][c]    = w_fc1[c][o]         (128 x 16)
// ---------------------------------------------------------------------------
__global__ void k_prep(const float* __restrict__ wp,    // [16][81]
                       const float* __restrict__ wfc1,  // [16][128]
                       float* __restrict__ wtc,         // [81][16]
                       float* __restrict__ wt1)         // [128][16]
{
    int tid = threadIdx.x;
    for (int i = tid; i < KSn * KSn * Cn; i += 256) {
        int t = i / Cn, c = i - t * Cn;
        wtc[i] = wp[c * (KSn * KSn) + t];
    }
    for (int i = tid; i < HIDn * Cn; i += 256) {
        int o = i / Cn, c = i - o * Cn;
        wt1[i] = wfc1[c * HIDn + o];
    }
}

// ---------------------------------------------------------------------------
// Kernel A: depthwise 9x9 reflect conv + bias, then fc0 (32 -> 128) + bias.
// x layout: NHWC ([B][H][W][16]); h layout: [B][128][HW].
// One thread per pixel. Block covers a 64x4 spatial tile for x-neighborhood
// reuse in L1/L2.
// ---------------------------------------------------------------------------
__global__ __launch_bounds__(256) void k_convfc0(
    const float* __restrict__ xin,    // [B][H][W][16]
    const float* __restrict__ wtc,    // [81][16]
    const float* __restrict__ bp,     // [16]
    const float* __restrict__ wfc0,   // [128][32]
    const float* __restrict__ bfc0,   // [128]
    float* __restrict__ hbuf)         // [B][128][HW]
{
    int tid = threadIdx.x;
    int bt  = blockIdx.x;                // 0..575
    int b   = bt / 144;
    int r   = bt - b * 144;
    int ty  = r / 3;
    int tx  = r - ty * 3;
    int x   = tx * 64 + (tid & 63);
    int y   = ty * 4 + (tid >> 6);
    int p   = y * Wn + x;

    // reflect indices (np.pad mode="reflect": -1 -> 1, H -> H-2)
    int syo[KSn], sxo[KSn];
#pragma unroll
    for (int d = 0; d < KSn; ++d) {
        int yy = y + d - PADn;
        yy = yy < 0 ? -yy : yy;
        yy = yy >= Hn ? 2 * Hn - 2 - yy : yy;
        syo[d] = yy * Wn;
        int xx = x + d - PADn;
        xx = xx < 0 ? -xx : xx;
        xx = xx >= Wn ? 2 * Wn - 2 - xx : xx;
        sxo[d] = xx;
    }

    const float* xbase = xin + (size_t)b * HWn * Cn;

    float y1[Cn];
#pragma unroll
    for (int c = 0; c < Cn; ++c) y1[c] = bp[c];

#pragma unroll
    for (int dy = 0; dy < KSn; ++dy) {
#pragma unroll
        for (int dx = 0; dx < KSn; ++dx) {
            int sp = syo[dy] + sxo[dx];
            const float4* src = (const float4*)(xbase + (size_t)sp * Cn);
            float4 v0 = src[0], v1 = src[1], v2 = src[2], v3 = src[3];
            const float* wr = wtc + (dy * KSn + dx) * Cn;  // wave-uniform -> s_load
            y1[0]  = fmaf(wr[0],  v0.x, y1[0]);
            y1[1]  = fmaf(wr[1],  v0.y, y1[1]);
            y1[2]  = fmaf(wr[2],  v0.z, y1[2]);
            y1[3]  = fmaf(wr[3],  v0.w, y1[3]);
            y1[4]  = fmaf(wr[4],  v1.x, y1[4]);
            y1[5]  = fmaf(wr[5],  v1.y, y1[5]);
            y1[6]  = fmaf(wr[6],  v1.z, y1[6]);
            y1[7]  = fmaf(wr[7],  v1.w, y1[7]);
            y1[8]  = fmaf(wr[8],  v2.x, y1[8]);
            y1[9]  = fmaf(wr[9],  v2.y, y1[9]);
            y1[10] = fmaf(wr[10], v2.z, y1[10]);
            y1[11] = fmaf(wr[11], v2.w, y1[11]);
            y1[12] = fmaf(wr[12], v3.x, y1[12]);
            y1[13] = fmaf(wr[13], v3.y, y1[13]);
            y1[14] = fmaf(wr[14], v3.z, y1[14]);
            y1[15] = fmaf(wr[15], v3.w, y1[15]);
        }
    }

    // dx = concat(x_center, y1)
    float dxv[2 * Cn];
    {
        const float4* src = (const float4*)(xbase + (size_t)p * Cn);
        float4 v0 = src[0], v1 = src[1], v2 = src[2], v3 = src[3];
        dxv[0]  = v0.x; dxv[1]  = v0.y; dxv[2]  = v0.z; dxv[3]  = v0.w;
        dxv[4]  = v1.x; dxv[5]  = v1.y; dxv[6]  = v1.z; dxv[7]  = v1.w;
        dxv[8]  = v2.x; dxv[9]  = v2.y; dxv[10] = v2.z; dxv[11] = v2.w;
        dxv[12] = v3.x; dxv[13] = v3.y; dxv[14] = v3.z; dxv[15] = v3.w;
    }
#pragma unroll
    for (int c = 0; c < Cn; ++c) dxv[Cn + c] = y1[c];

    float* hout = hbuf + (size_t)b * HIDn * HWn + p;
#pragma unroll 4
    for (int o = 0; o < HIDn; ++o) {
        const float* wr = wfc0 + o * 2 * Cn;   // wave-uniform row -> s_load
        float acc = bfc0[o];
#pragma unroll
        for (int c = 0; c < 2 * Cn; ++c) acc = fmaf(wr[c], dxv[c], acc);
        hout[(size_t)o * HWn] = acc;
    }
}

// ---------------------------------------------------------------------------
// Kernel S: per-channel mean/var over (B,H,W), emit scale/shift:
//   scale = gamma * rsqrt(var+eps); shift = beta - mean*scale
// One block per hidden channel. Deterministic (no atomics).
// ---------------------------------------------------------------------------
__global__ __launch_bounds__(512) void k_stats(
    const float* __restrict__ hbuf,   // [B][128][HW]
    const float* __restrict__ gamma,
    const float* __restrict__ beta,
    float* __restrict__ scale,
    float* __restrict__ shift)
{
    int o   = blockIdx.x;
    int tid = threadIdx.x;
    float s = 0.f, sq = 0.f;
    for (int b = 0; b < Bn; ++b) {
        const float4* src = (const float4*)(hbuf + ((size_t)b * HIDn + o) * HWn);
        for (int i = tid; i < HWn / 4; i += 512) {
            float4 v = src[i];
            s  += v.x + v.y + v.z + v.w;
            sq += v.x * v.x + v.y * v.y + v.z * v.z + v.w * v.w;
        }
    }
#pragma unroll
    for (int off = 32; off > 0; off >>= 1) {
        s  += __shfl_xor(s, off, 64);
        sq += __shfl_xor(sq, off, 64);
    }
    __shared__ float rs[8], rq[8];
    int wv = tid >> 6;
    if ((tid & 63) == 0) { rs[wv] = s; rq[wv] = sq; }
    __syncthreads();
    if (tid == 0) {
        float S = 0.f, Q = 0.f;
#pragma unroll
        for (int w = 0; w < 8; ++w) { S += rs[w]; Q += rq[w]; }
        float mean = S * (1.0f / BHWn);
        float var  = Q * (1.0f / BHWn) - mean * mean;
        float rstd = rsqrtf(var + EPSf);
        float sc   = gamma[o] * rstd;
        scale[o] = sc;
        shift[o] = beta[o] - mean * sc;
    }
}

// ---------------------------------------------------------------------------
// Kernel U: hn = relu(h*scale+shift); d = fc1(hn); x' = x + d*(u>0.5),
// channel 0 frozen. In-place safe (each thread owns its pixel).
// ---------------------------------------------------------------------------
__global__ __launch_bounds__(256) void k_update(
    const float* __restrict__ xin,    // [B][H][W][16]
    const float* __restrict__ hbuf,   // [B][128][HW]
    const float* __restrict__ scale,  // [128]
    const float* __restrict__ shift,  // [128]
    const float* __restrict__ wt1,    // [128][16]
    const float* __restrict__ u,      // [B][HW] (this step's slice)
    float* __restrict__ xout)         // [B][H][W][16]
{
    int gid = blockIdx.x * 256 + threadIdx.x;
    int b   = gid / HWn;
    int p   = gid - b * HWn;
    const float* hsrc = hbuf + (size_t)b * HIDn * HWn + p;

    float acc[Cn];
#pragma unroll
    for (int c = 0; c < Cn; ++c) acc[c] = 0.f;

#pragma unroll 4
    for (int o = 0; o < HIDn; ++o) {
        float hv = hsrc[(size_t)o * HWn];
        float hn = fmaf(hv, scale[o], shift[o]);   // scale/shift wave-uniform
        hn = fmaxf(hn, 0.f);
        const float* wr = wt1 + o * Cn;            // wave-uniform row -> s_load
#pragma unroll
        for (int c = 0; c < Cn; ++c) acc[c] = fmaf(wr[c], hn, acc[c]);
    }

    float m = u[gid] > FIREf ? 1.f : 0.f;
    const float4* xs = (const float4*)(xin + (size_t)gid * Cn);
    float4 v0 = xs[0], v1 = xs[1], v2 = xs[2], v3 = xs[3];
    // channel 0 frozen (INPUT_CHANNELS=1)
    v0.y = fmaf(acc[1], m, v0.y);
    v0.z = fmaf(acc[2], m, v0.z);
    v0.w = fmaf(acc[3], m, v0.w);
    v1.x = fmaf(acc[4], m, v1.x);
    v1.y = fmaf(acc[5], m, v1.y);
    v1.z = fmaf(acc[6], m, v1.z);
    v1.w = fmaf(acc[7], m, v1.w);
    v2.x = fmaf(acc[8], m, v2.x);
    v2.y = fmaf(acc[9], m, v2.y);
    v2.z = fmaf(acc[10], m, v2.z);
    v2.w = fmaf(acc[11], m, v2.w);
    v3.x = fmaf(acc[12], m, v3.x);
    v3.y = fmaf(acc[13], m, v3.y);
    v3.z = fmaf(acc[14], m, v3.z);
    v3.w = fmaf(acc[15], m, v3.w);
    float4* xd = (float4*)(xout + (size_t)gid * Cn);
    xd[0] = v0; xd[1] = v1; xd[2] = v2; xd[3] = v3;
}

// ---------------------------------------------------------------------------
extern "C" void kernel_launch(void* const* d_in, const int* in_sizes, int n_in,
                              void* d_out, int out_size, void* d_ws, size_t ws_size,
                              hipStream_t stream) {
    const float* x0   = (const float*)d_in[0];  // [4][192][192][16] NHWC
    const float* ru   = (const float*)d_in[1];  // [10][4][1][192][192]
    const float* wp   = (const float*)d_in[2];  // [16][1][9][9]
    const float* bp   = (const float*)d_in[3];  // [16]
    const float* wfc0 = (const float*)d_in[4];  // [128][32]
    const float* bfc0 = (const float*)d_in[5];  // [128]
    const float* wfc1 = (const float*)d_in[6];  // [16][128]
    const float* gm   = (const float*)d_in[7];  // [128]
    const float* bt   = (const float*)d_in[8];  // [128]

    float* ws    = (float*)d_ws;
    float* hbuf  = ws;                                   // 18,874,368 floats
    float* xbuf  = hbuf + (size_t)Bn * HIDn * HWn;       //  2,359,296 floats
    float* wtc   = xbuf + (size_t)BHWn * Cn;             //  1296 (pad to 1312)
    float* wt1   = wtc + 1312;                           //  2048
    float* scale = wt1 + 2048;                           //  128
    float* shift = scale + 128;                          //  128

    k_prep<<<1, 256, 0, stream>>>(wp, wfc1, wtc, wt1);

    const float* xcur = x0;
    for (int s = 0; s < STEPSn; ++s) {
        k_convfc0<<<576, 256, 0, stream>>>(xcur, wtc, bp, wfc0, bfc0, hbuf);
        k_stats<<<HIDn, 512, 0, stream>>>(hbuf, gm, bt, scale, shift);
        float* xo = (s == STEPSn - 1) ? (float*)d_out : xbuf;
        k_update<<<576, 256, 0, stream>>>(xcur, hbuf, scale, shift, wt1,
                                          ru + (size_t)s * BHWn, xo);
        xcur = xo;
    }
}

// Round 2
// 937.754 us; speedup vs baseline: 1.8550x; 1.8550x over previous
//
#include <hip/hip_runtime.h>

// Problem constants
constexpr int Bn    = 4;
constexpr int Hn    = 192;
constexpr int Wn    = 192;
constexpr int Cn    = 16;     // state channels
constexpr int HIDn  = 128;    // hidden channels
constexpr int HWn   = Hn * Wn;        // 36864
constexpr int BHWn  = Bn * HWn;       // 147456
constexpr int STEPSn = 10;
constexpr int PADn  = 4;
constexpr int KSn   = 9;
constexpr float EPSf  = 1e-5f;
constexpr float FIREf = 0.5f;

constexpr int PXB   = 64;             // pixels per block
constexpr int BLKS  = BHWn / PXB;     // 2304 blocks
constexpr int BPB   = HWn / PXB;      // 576 blocks per batch image

// ---------------------------------------------------------------------------
// One-time weight transposes:
//   wtc[tap][c] = w_p0[c][tap]   (81 x 16)
//   wt1[o][c]   = w_fc1[c][o]    (128 x 16)
// ---------------------------------------------------------------------------
__global__ void k_prep(const float* __restrict__ wp,    // [16][81]
                       const float* __restrict__ wfc1,  // [16][128]
                       float* __restrict__ wtc,         // [81][16]
                       float* __restrict__ wt1)         // [128][16]
{
    int tid = threadIdx.x;
    for (int i = tid; i < KSn * KSn * Cn; i += 256) {
        int t = i / Cn, c = i - t * Cn;
        wtc[i] = wp[c * (KSn * KSn) + t];
    }
    for (int i = tid; i < HIDn * Cn; i += 256) {
        int o = i / Cn, c = i - o * Cn;
        wt1[i] = wfc1[c * HIDn + o];
    }
}

// ---------------------------------------------------------------------------
// Kernel A: depthwise 9x9 reflect conv + bias, then fc0 (32->128) + bias.
// Block = 4 waves x 64 px (one 64-px row chunk).
// Phase 1: wave w computes conv channel-quad w for all 64 px (lane = px).
// Phase 2: wave w computes fc0 outputs o in [32w, 32w+32) -- o wave-uniform,
//          weights via scalar loads; dxv via LDS [64][33] (conflict-free).
// ---------------------------------------------------------------------------
__global__ __launch_bounds__(256) void k_convfc0(
    const float* __restrict__ xin,    // [B][H][W][16]
    const float* __restrict__ wtc,    // [81][16]
    const float* __restrict__ bp,     // [16]
    const float* __restrict__ wfc0,   // [128][32]
    const float* __restrict__ bfc0,   // [128]
    float* __restrict__ hbuf)         // [B][128][HW]
{
    __shared__ float sdx[PXB][33];    // dxv per pixel, padded

    int tid  = threadIdx.x;
    int lane = tid & 63;
    int w    = __builtin_amdgcn_readfirstlane(tid >> 6);  // wave id, uniform

    int blk = blockIdx.x;             // 0..2303
    int b   = blk / BPB;
    int pb  = (blk - b * BPB) * PXB;  // base pixel within image
    int y   = pb / Wn;                // uniform per block (PXB divides Wn*rows cleanly: 3 chunks/row)
    int x   = (pb - y * Wn) + lane;
    int p   = pb + lane;

    // reflect indices (np.pad "reflect": -1 -> 1, H -> 2H-2-H)
    int syo[KSn], sxo[KSn];
#pragma unroll
    for (int d = 0; d < KSn; ++d) {
        int yy = y + d - PADn;
        yy = yy < 0 ? -yy : yy;
        yy = yy >= Hn ? 2 * Hn - 2 - yy : yy;
        syo[d] = yy * Wn;
        int xx = x + d - PADn;
        xx = xx < 0 ? -xx : xx;
        xx = xx >= Wn ? 2 * Wn - 2 - xx : xx;
        sxo[d] = xx;
    }

    const float* xbase = xin + (size_t)b * HWn * Cn;

    // ---- Phase 1: depthwise conv, channel quad w ----
    float4 acc;
    {
        float4 bq = *(const float4*)(bp + 4 * w);   // uniform -> s_load
        acc = bq;
    }
#pragma unroll
    for (int dy = 0; dy < KSn; ++dy) {
#pragma unroll
        for (int dx = 0; dx < KSn; ++dx) {
            int sp = syo[dy] + sxo[dx];
            float4 v  = *(const float4*)(xbase + (size_t)sp * Cn + 4 * w);
            float4 wq = *(const float4*)(wtc + (dy * KSn + dx) * Cn + 4 * w); // uniform
            acc.x = fmaf(wq.x, v.x, acc.x);
            acc.y = fmaf(wq.y, v.y, acc.y);
            acc.z = fmaf(wq.z, v.z, acc.z);
            acc.w = fmaf(wq.w, v.w, acc.w);
        }
    }

    // center x quad + conv quad -> LDS dxv
    {
        float4 cv = *(const float4*)(xbase + (size_t)p * Cn + 4 * w);
        sdx[lane][4 * w + 0] = cv.x;
        sdx[lane][4 * w + 1] = cv.y;
        sdx[lane][4 * w + 2] = cv.z;
        sdx[lane][4 * w + 3] = cv.w;
        sdx[lane][Cn + 4 * w + 0] = acc.x;
        sdx[lane][Cn + 4 * w + 1] = acc.y;
        sdx[lane][Cn + 4 * w + 2] = acc.z;
        sdx[lane][Cn + 4 * w + 3] = acc.w;
    }
    __syncthreads();

    // ---- Phase 2: fc0, outputs o in [32w, 32w+32) ----
    float dv[2 * Cn];
#pragma unroll
    for (int c = 0; c < 2 * Cn; ++c) dv[c] = sdx[lane][c];

    float* hout = hbuf + (size_t)b * HIDn * HWn + p;
#pragma unroll 4
    for (int j = 0; j < 32; ++j) {
        int o = w * 32 + j;                        // wave-uniform
        const float* wr = wfc0 + o * 2 * Cn;       // -> s_load rows
        float a = bfc0[o];
#pragma unroll
        for (int c = 0; c < 2 * Cn; ++c) a = fmaf(wr[c], dv[c], a);
        hout[(size_t)o * HWn] = a;
    }
}

// ---------------------------------------------------------------------------
// Kernel S: partial per-channel sums. Block = (o, chunk k of 8):
//   b = k>>1, half = k&1 -> one half-plane (18432 floats) per block.
// Writes (sum, sumsq) to part[o*8+k]. Deterministic.
// ---------------------------------------------------------------------------
__global__ __launch_bounds__(256) void k_stats(
    const float* __restrict__ hbuf,   // [B][128][HW]
    float2* __restrict__ part)        // [128][8]
{
    int o    = blockIdx.x >> 3;
    int k    = blockIdx.x & 7;
    int b    = k >> 1;
    int half = k & 1;
    int tid  = threadIdx.x;

    const float4* src = (const float4*)(hbuf + ((size_t)b * HIDn + o) * HWn
                                        + half * (HWn / 2));
    float s = 0.f, q = 0.f;
#pragma unroll
    for (int j = 0; j < 18; ++j) {            // 18*256 = 4608 = 18432/4
        float4 v = src[tid + j * 256];
        s += v.x + v.y + v.z + v.w;
        q += v.x * v.x + v.y * v.y + v.z * v.z + v.w * v.w;
    }
#pragma unroll
    for (int off = 32; off > 0; off >>= 1) {
        s += __shfl_xor(s, off, 64);
        q += __shfl_xor(q, off, 64);
    }
    __shared__ float rs[4], rq[4];
    int wv = tid >> 6;
    if ((tid & 63) == 0) { rs[wv] = s; rq[wv] = q; }
    __syncthreads();
    if (tid == 0) {
        part[blockIdx.x] = make_float2(rs[0] + rs[1] + rs[2] + rs[3],
                                       rq[0] + rq[1] + rq[2] + rq[3]);
    }
}

// ---------------------------------------------------------------------------
// Kernel U: prologue combines stats partials -> scale/shift in LDS.
// Phase 1: wave w computes partial acc[16] over o in [32w,32w+32).
// Phase 2: combine 4 wave-partials via LDS; thread (px=lane, quad=w) applies
// mask and writes its x float4. Channel 0 frozen. In-place safe.
// ---------------------------------------------------------------------------
__global__ __launch_bounds__(256) void k_update(
    const float* __restrict__ xin,    // [B][H][W][16]
    const float* __restrict__ hbuf,   // [B][128][HW]
    const float2* __restrict__ part,  // [128][8]
    const float* __restrict__ gamma,
    const float* __restrict__ beta,
    const float* __restrict__ wt1,    // [128][16]
    const float* __restrict__ u,      // [B][HW] (this step's slice)
    float* __restrict__ xout)         // [B][H][W][16]
{
    __shared__ float sc[HIDn], sh[HIDn];
    __shared__ float pacc[4][PXB][17];

    int tid  = threadIdx.x;
    int lane = tid & 63;
    int w    = __builtin_amdgcn_readfirstlane(tid >> 6);

    if (tid < HIDn) {
        float s = 0.f, q = 0.f;
#pragma unroll
        for (int k = 0; k < 8; ++k) {
            float2 v = part[tid * 8 + k];
            s += v.x; q += v.y;
        }
        float mean = s * (1.0f / BHWn);
        float var  = q * (1.0f / BHWn) - mean * mean;
        float g    = gamma[tid] * rsqrtf(var + EPSf);
        sc[tid] = g;
        sh[tid] = beta[tid] - mean * g;
    }
    __syncthreads();

    int blk = blockIdx.x;
    int b   = blk / BPB;
    int pb  = (blk - b * BPB) * PXB;
    int p   = pb + lane;

    const float* hsrc = hbuf + (size_t)b * HIDn * HWn + p;

    float acc[Cn];
#pragma unroll
    for (int c = 0; c < Cn; ++c) acc[c] = 0.f;

#pragma unroll 4
    for (int j = 0; j < 32; ++j) {
        int o = w * 32 + j;                       // wave-uniform
        float hv = hsrc[(size_t)o * HWn];
        float hn = fmaxf(fmaf(hv, sc[o], sh[o]), 0.f);
        const float* wr = wt1 + o * Cn;           // -> s_load
#pragma unroll
        for (int c = 0; c < Cn; ++c) acc[c] = fmaf(wr[c], hn, acc[c]);
    }

#pragma unroll
    for (int c = 0; c < Cn; ++c) pacc[w][lane][c] = acc[c];
    __syncthreads();

    // finalize channel quad w for pixel lane
    float4 r = make_float4(0.f, 0.f, 0.f, 0.f);
#pragma unroll
    for (int w2 = 0; w2 < 4; ++w2) {
        r.x += pacc[w2][lane][4 * w + 0];
        r.y += pacc[w2][lane][4 * w + 1];
        r.z += pacc[w2][lane][4 * w + 2];
        r.w += pacc[w2][lane][4 * w + 3];
    }
    if (w == 0) r.x = 0.f;                        // channel 0 frozen

    float m = u[(size_t)b * HWn + p] > FIREf ? 1.f : 0.f;
    size_t xoff = ((size_t)b * HWn + p) * Cn + 4 * w;
    float4 xv = *(const float4*)(xin + xoff);
    xv.x = fmaf(r.x, m, xv.x);
    xv.y = fmaf(r.y, m, xv.y);
    xv.z = fmaf(r.z, m, xv.z);
    xv.w = fmaf(r.w, m, xv.w);
    *(float4*)(xout + xoff) = xv;
}

// ---------------------------------------------------------------------------
extern "C" void kernel_launch(void* const* d_in, const int* in_sizes, int n_in,
                              void* d_out, int out_size, void* d_ws, size_t ws_size,
                              hipStream_t stream) {
    const float* x0   = (const float*)d_in[0];  // [4][192][192][16] NHWC
    const float* ru   = (const float*)d_in[1];  // [10][4][1][192][192]
    const float* wp   = (const float*)d_in[2];  // [16][1][9][9]
    const float* bp   = (const float*)d_in[3];  // [16]
    const float* wfc0 = (const float*)d_in[4];  // [128][32]
    const float* bfc0 = (const float*)d_in[5];  // [128]
    const float* wfc1 = (const float*)d_in[6];  // [16][128]
    const float* gm   = (const float*)d_in[7];  // [128]
    const float* bt   = (const float*)d_in[8];  // [128]

    float* ws    = (float*)d_ws;
    float* hbuf  = ws;                                   // 18,874,368 floats
    float* xbuf  = hbuf + (size_t)Bn * HIDn * HWn;       //  2,359,296 floats
    float* wtc   = xbuf + (size_t)BHWn * Cn;             //  1296 (pad 1312)
    float* wt1   = wtc + 1312;                           //  2048
    float2* part = (float2*)(wt1 + 2048);                //  128*8 float2

    k_prep<<<1, 256, 0, stream>>>(wp, wfc1, wtc, wt1);

    const float* xcur = x0;
    for (int s = 0; s < STEPSn; ++s) {
        k_convfc0<<<BLKS, 256, 0, stream>>>(xcur, wtc, bp, wfc0, bfc0, hbuf);
        k_stats<<<HIDn * 8, 256, 0, stream>>>(hbuf, part);
        float* xo = (s == STEPSn - 1) ? (float*)d_out : xbuf;
        k_update<<<BLKS, 256, 0, stream>>>(xcur, hbuf, part, gm, bt, wt1,
                                           ru + (size_t)s * BHWn, xo);
        xcur = xo;
    }
}

// Round 3
// 681.625 us; speedup vs baseline: 2.5520x; 1.3758x over previous
//
#include <hip/hip_runtime.h>

// Problem constants
constexpr int Bn    = 4;
constexpr int Hn    = 192;
constexpr int Wn    = 192;
constexpr int Cn    = 16;     // state channels
constexpr int HIDn  = 128;    // hidden channels
constexpr int HWn   = Hn * Wn;        // 36864
constexpr int BHWn  = Bn * HWn;       // 147456
constexpr int STEPSn = 10;
constexpr int PADn  = 4;
constexpr int KSn   = 9;
constexpr float EPSf  = 1e-5f;
constexpr float FIREf = 0.5f;

// conv kernel geometry: block tile = 64 cols x 2 rows (128 px), 4 waves (quads)
constexpr int TROWS = 2;
constexpr int TPX   = 64 * TROWS;                 // 128 px per block
constexpr int CBLKS = BHWn / TPX;                 // 1152 blocks
constexpr int RTPI  = HWn / TPX;                  // 288 tiles per image (96 row-tiles x 3 col-tiles)

typedef __attribute__((ext_vector_type(8))) short short8;
typedef __attribute__((ext_vector_type(4))) float f32x4;

static __device__ __forceinline__ short f2bf(float f) {
    union { float f; unsigned u; } v; v.f = f;
    unsigned r = v.u + 0x7FFFu + ((v.u >> 16) & 1u);   // RNE
    return (short)(r >> 16);
}

static __device__ __forceinline__ int refl(int v, int n) {
    v = v < 0 ? -v : v;
    v = v >= n ? 2 * n - 2 - v : v;
    return v;
}

// ---------------------------------------------------------------------------
// One-time weight prep:
//   wtc[tap][c]        = w_p0[c][tap]                     (81 x 16 f32)
//   wt1[o][c]          = w_fc1[c][o]                      (128 x 16 f32)
//   bfrag[nt][l][j]    = bf16(wfc0[nt*16+(l&15)][(l>>4)*8+j])   (8 x 64 x 8 bf16)
// ---------------------------------------------------------------------------
__global__ void k_prep(const float* __restrict__ wp,    // [16][81]
                       const float* __restrict__ wfc1,  // [16][128]
                       const float* __restrict__ wfc0,  // [128][32]
                       float* __restrict__ wtc,
                       float* __restrict__ wt1,
                       short* __restrict__ bfrag)
{
    int tid = threadIdx.x;
    for (int i = tid; i < KSn * KSn * Cn; i += 256) {
        int t = i / Cn, c = i - t * Cn;
        wtc[i] = wp[c * (KSn * KSn) + t];
    }
    for (int i = tid; i < HIDn * Cn; i += 256) {
        int o = i / Cn, c = i - o * Cn;
        wt1[i] = wfc1[c * HIDn + o];
    }
    for (int i = tid; i < 8 * 64 * 8; i += 256) {
        int nt = i >> 9;
        int rem = i & 511;
        int l = rem >> 3, j = rem & 7;
        int n = nt * 16 + (l & 15);
        int k = (l >> 4) * 8 + j;
        bfrag[i] = f2bf(wfc0[n * 32 + k]);
    }
}

// ---------------------------------------------------------------------------
// Kernel A: depthwise 9x9 reflect conv (fp32, VY=2) + fc0 via bf16 MFMA.
// Wave w = channel-quad w for conv (weights wave-uniform -> s_load).
// dxv staged fp32 in LDS [128][33] (bank-conflict-free), then per-wave
// mfma_f32_16x16x32_bf16 over 2 m-tiles x 8 n-tiles. h stored fp32 [b][o][p].
// ---------------------------------------------------------------------------
__global__ __launch_bounds__(256) void k_convfc0(
    const float* __restrict__ xin,    // [B][H][W][16]
    const float* __restrict__ wtc,    // [81][16]
    const float* __restrict__ bp,     // [16]
    const short* __restrict__ bfrag,  // [8][64][8] bf16
    const float* __restrict__ bfc0,   // [128]
    float* __restrict__ hbuf)         // [B][128][HW]
{
    __shared__ float sdx[TPX][33];

    int tid  = threadIdx.x;
    int lane = tid & 63;
    int w    = __builtin_amdgcn_readfirstlane(tid >> 6);

    int blk = blockIdx.x;             // 0..1151
    int b   = blk / RTPI;
    int t   = blk - b * RTPI;
    int ty  = t / 3;                  // 0..95
    int tx  = t - ty * 3;             // 0..2
    int y0  = ty * TROWS;
    int x0  = tx * 64;
    int col = x0 + lane;

    // 32-bit float4 indices: x element = (yy*192 + xx)*4 + quad
    int srow[10], scol[KSn];
#pragma unroll
    for (int ri = 0; ri < 10; ++ri)
        srow[ri] = refl(y0 + ri - PADn, Hn) * (Wn * 4);
#pragma unroll
    for (int dx = 0; dx < KSn; ++dx)
        scol[dx] = refl(col + dx - PADn, Wn) * 4 + w;

    const float4* xb4 = (const float4*)(xin + (size_t)b * HWn * Cn);
    const float4* wt4 = (const float4*)wtc;

    float4 bq = ((const float4*)bp)[w];            // uniform
    float4 acc0 = bq, acc1 = bq;
    float4 cen0, cen1;

#pragma unroll
    for (int ri = 0; ri < 10; ++ri) {
        float4 v[KSn];
#pragma unroll
        for (int dx = 0; dx < KSn; ++dx) v[dx] = xb4[srow[ri] + scol[dx]];
        if (ri == 4) cen0 = v[4];
        if (ri == 5) cen1 = v[4];
#pragma unroll
        for (int dx = 0; dx < KSn; ++dx) {
            if (ri <= 8) {
                float4 wq = wt4[(ri * KSn + dx) * 4 + w];       // s_load
                acc0.x = fmaf(wq.x, v[dx].x, acc0.x);
                acc0.y = fmaf(wq.y, v[dx].y, acc0.y);
                acc0.z = fmaf(wq.z, v[dx].z, acc0.z);
                acc0.w = fmaf(wq.w, v[dx].w, acc0.w);
            }
            if (ri >= 1) {
                float4 wq = wt4[((ri - 1) * KSn + dx) * 4 + w]; // s_load
                acc1.x = fmaf(wq.x, v[dx].x, acc1.x);
                acc1.y = fmaf(wq.y, v[dx].y, acc1.y);
                acc1.z = fmaf(wq.z, v[dx].z, acc1.z);
                acc1.w = fmaf(wq.w, v[dx].w, acc1.w);
            }
        }
    }

    // stage dxv fp32: px row0 = lane, row1 = 64+lane; ch 0-15 = x, 16-31 = conv
    sdx[lane][4 * w + 0] = cen0.x;  sdx[lane][4 * w + 1] = cen0.y;
    sdx[lane][4 * w + 2] = cen0.z;  sdx[lane][4 * w + 3] = cen0.w;
    sdx[lane][Cn + 4 * w + 0] = acc0.x;  sdx[lane][Cn + 4 * w + 1] = acc0.y;
    sdx[lane][Cn + 4 * w + 2] = acc0.z;  sdx[lane][Cn + 4 * w + 3] = acc0.w;
    sdx[64 + lane][4 * w + 0] = cen1.x;  sdx[64 + lane][4 * w + 1] = cen1.y;
    sdx[64 + lane][4 * w + 2] = cen1.z;  sdx[64 + lane][4 * w + 3] = cen1.w;
    sdx[64 + lane][Cn + 4 * w + 0] = acc1.x;  sdx[64 + lane][Cn + 4 * w + 1] = acc1.y;
    sdx[64 + lane][Cn + 4 * w + 2] = acc1.z;  sdx[64 + lane][Cn + 4 * w + 3] = acc1.w;
    __syncthreads();

    // ---- MFMA fc0: wave w owns px chunk [32w, 32w+32) x all 128 outputs ----
    int l15 = lane & 15;
    int kg  = lane >> 4;

    short8 A[2];
#pragma unroll
    for (int mt = 0; mt < 2; ++mt) {
        int px = 32 * w + mt * 16 + l15;
#pragma unroll
        for (int j = 0; j < 8; ++j)
            A[mt][j] = f2bf(sdx[px][kg * 8 + j]);
    }

    short8 Bf[8];
    const short8* bgp = (const short8*)bfrag;
#pragma unroll
    for (int nt = 0; nt < 8; ++nt) Bf[nt] = bgp[nt * 64 + lane];

#pragma unroll
    for (int nt = 0; nt < 8; ++nt) {
        int o = nt * 16 + l15;
        float bn = bfc0[o];
#pragma unroll
        for (int mt = 0; mt < 2; ++mt) {
            f32x4 c = {bn, bn, bn, bn};
            c = __builtin_amdgcn_mfma_f32_16x16x32_bf16(A[mt], Bf[nt], c, 0, 0, 0);
            int pxb = 32 * w + 16 * mt + 4 * kg;            // 4-aligned, same row
            int p   = (y0 + (pxb >> 6)) * Wn + x0 + (pxb & 63);
            *(f32x4*)(hbuf + (size_t)(b * HIDn + o) * HWn + p) = c;
        }
    }
}

// ---------------------------------------------------------------------------
// Kernel S: partial per-channel sums (unchanged).
// ---------------------------------------------------------------------------
__global__ __launch_bounds__(256) void k_stats(
    const float* __restrict__ hbuf,   // [B][128][HW]
    float2* __restrict__ part)        // [128][8]
{
    int o    = blockIdx.x >> 3;
    int k    = blockIdx.x & 7;
    int b    = k >> 1;
    int half = k & 1;
    int tid  = threadIdx.x;

    const float4* src = (const float4*)(hbuf + ((size_t)b * HIDn + o) * HWn
                                        + half * (HWn / 2));
    float s = 0.f, q = 0.f;
#pragma unroll
    for (int j = 0; j < 18; ++j) {
        float4 v = src[tid + j * 256];
        s += v.x + v.y + v.z + v.w;
        q += v.x * v.x + v.y * v.y + v.z * v.z + v.w * v.w;
    }
#pragma unroll
    for (int off = 32; off > 0; off >>= 1) {
        s += __shfl_xor(s, off, 64);
        q += __shfl_xor(q, off, 64);
    }
    __shared__ float rs[4], rq[4];
    int wv = tid >> 6;
    if ((tid & 63) == 0) { rs[wv] = s; rq[wv] = q; }
    __syncthreads();
    if (tid == 0) {
        part[blockIdx.x] = make_float2(rs[0] + rs[1] + rs[2] + rs[3],
                                       rq[0] + rq[1] + rq[2] + rq[3]);
    }
}

// ---------------------------------------------------------------------------
// Kernel U: BN + ReLU + fc1 + masked update (unchanged).
// ---------------------------------------------------------------------------
__global__ __launch_bounds__(256) void k_update(
    const float* __restrict__ xin,    // [B][H][W][16]
    const float* __restrict__ hbuf,   // [B][128][HW]
    const float2* __restrict__ part,  // [128][8]
    const float* __restrict__ gamma,
    const float* __restrict__ beta,
    const float* __restrict__ wt1,    // [128][16]
    const float* __restrict__ u,      // [B][HW]
    float* __restrict__ xout)         // [B][H][W][16]
{
    __shared__ float sc[HIDn], sh[HIDn];
    __shared__ float pacc[4][64][17];

    int tid  = threadIdx.x;
    int lane = tid & 63;
    int w    = __builtin_amdgcn_readfirstlane(tid >> 6);

    if (tid < HIDn) {
        float s = 0.f, q = 0.f;
#pragma unroll
        for (int k = 0; k < 8; ++k) {
            float2 v = part[tid * 8 + k];
            s += v.x; q += v.y;
        }
        float mean = s * (1.0f / BHWn);
        float var  = q * (1.0f / BHWn) - mean * mean;
        float g    = gamma[tid] * rsqrtf(var + EPSf);
        sc[tid] = g;
        sh[tid] = beta[tid] - mean * g;
    }
    __syncthreads();

    int blk = blockIdx.x;
    int b   = blk / (HWn / 64);
    int pb  = (blk - b * (HWn / 64)) * 64;
    int p   = pb + lane;

    const float* hsrc = hbuf + (size_t)b * HIDn * HWn + p;

    float acc[Cn];
#pragma unroll
    for (int c = 0; c < Cn; ++c) acc[c] = 0.f;

#pragma unroll 4
    for (int j = 0; j < 32; ++j) {
        int o = w * 32 + j;
        float hv = hsrc[(size_t)o * HWn];
        float hn = fmaxf(fmaf(hv, sc[o], sh[o]), 0.f);
        const float* wr = wt1 + o * Cn;
#pragma unroll
        for (int c = 0; c < Cn; ++c) acc[c] = fmaf(wr[c], hn, acc[c]);
    }

#pragma unroll
    for (int c = 0; c < Cn; ++c) pacc[w][lane][c] = acc[c];
    __syncthreads();

    float4 r = make_float4(0.f, 0.f, 0.f, 0.f);
#pragma unroll
    for (int w2 = 0; w2 < 4; ++w2) {
        r.x += pacc[w2][lane][4 * w + 0];
        r.y += pacc[w2][lane][4 * w + 1];
        r.z += pacc[w2][lane][4 * w + 2];
        r.w += pacc[w2][lane][4 * w + 3];
    }
    if (w == 0) r.x = 0.f;                        // channel 0 frozen

    float m = u[(size_t)b * HWn + p] > FIREf ? 1.f : 0.f;
    size_t xoff = ((size_t)b * HWn + p) * Cn + 4 * w;
    float4 xv = *(const float4*)(xin + xoff);
    xv.x = fmaf(r.x, m, xv.x);
    xv.y = fmaf(r.y, m, xv.y);
    xv.z = fmaf(r.z, m, xv.z);
    xv.w = fmaf(r.w, m, xv.w);
    *(float4*)(xout + xoff) = xv;
}

// ---------------------------------------------------------------------------
extern "C" void kernel_launch(void* const* d_in, const int* in_sizes, int n_in,
                              void* d_out, int out_size, void* d_ws, size_t ws_size,
                              hipStream_t stream) {
    const float* x0   = (const float*)d_in[0];
    const float* ru   = (const float*)d_in[1];
    const float* wp   = (const float*)d_in[2];
    const float* bp   = (const float*)d_in[3];
    const float* wfc0 = (const float*)d_in[4];
    const float* bfc0 = (const float*)d_in[5];
    const float* wfc1 = (const float*)d_in[6];
    const float* gm   = (const float*)d_in[7];
    const float* bt   = (const float*)d_in[8];

    float* ws    = (float*)d_ws;
    float* hbuf  = ws;                                   // 18,874,368 f
    float* xbuf  = hbuf + (size_t)Bn * HIDn * HWn;       //  2,359,296 f
    float* wtc   = xbuf + (size_t)BHWn * Cn;             //  1312 f (pad)
    float* wt1   = wtc + 1312;                           //  2048 f
    float2* part = (float2*)(wt1 + 2048);                //  1024 f2 = 2048 f
    short* bfrag = (short*)(wt1 + 2048 + 2048);          //  4096 bf16

    k_prep<<<1, 256, 0, stream>>>(wp, wfc1, wfc0, wtc, wt1, bfrag);

    const float* xcur = x0;
    for (int s = 0; s < STEPSn; ++s) {
        k_convfc0<<<CBLKS, 256, 0, stream>>>(xcur, wtc, bp, bfrag, bfc0, hbuf);
        k_stats<<<HIDn * 8, 256, 0, stream>>>(hbuf, part);
        float* xo = (s == STEPSn - 1) ? (float*)d_out : xbuf;
        k_update<<<BHWn / 64, 256, 0, stream>>>(xcur, hbuf, part, gm, bt, wt1,
                                                ru + (size_t)s * BHWn, xo);
        xcur = xo;
    }
}

// Round 4
// 448.465 us; speedup vs baseline: 3.8788x; 1.5199x over previous
//
#include <hip/hip_runtime.h>

// Problem constants
constexpr int Bn    = 4;
constexpr int Hn    = 192;
constexpr int Wn    = 192;
constexpr int Cn    = 16;
constexpr int HIDn  = 128;
constexpr int HWn   = Hn * Wn;        // 36864
constexpr int BHWn  = Bn * HWn;       // 147456
constexpr int STEPSn = 10;
constexpr int PADn  = 4;
constexpr int KSn   = 9;
constexpr float EPSf  = 1e-5f;
constexpr float FIREf = 0.5f;

// fused kernel geometry: 64 cols x 3 rows per block, 4 waves (channel quads)
constexpr int VY    = 3;
constexpr int SROWS = VY + 8;         // 11 staged rows
constexpr int SCOLS = 72;             // 64 + 8 halo cols
constexpr int TPXc  = 64 * VY;        // 192 px per block
constexpr int CBLK  = BHWn / TPXc;    // 768 blocks
constexpr int TPIc  = HWn / TPXc;     // 192 tiles per image

typedef __attribute__((ext_vector_type(8))) short short8;
typedef __attribute__((ext_vector_type(4))) float f32x4;

static __device__ __forceinline__ unsigned f2bfu(float f) {
    union { float f; unsigned u; } v; v.f = f;
    return (v.u + 0x7FFFu + ((v.u >> 16) & 1u)) >> 16;   // RNE, as u32
}
static __device__ __forceinline__ short f2bf(float f) { return (short)f2bfu(f); }
static __device__ __forceinline__ float bf2f(unsigned short h) {
    union { unsigned u; float f; } v; v.u = ((unsigned)h) << 16;
    return v.f;
}
static __device__ __forceinline__ int refl(int v, int n) {
    v = v < 0 ? -v : v;
    v = v >= n ? 2 * n - 2 - v : v;
    return v;
}

// ---------------------------------------------------------------------------
// One-time weight prep (unchanged from round 3)
// ---------------------------------------------------------------------------
__global__ void k_prep(const float* __restrict__ wp,    // [16][81]
                       const float* __restrict__ wfc1,  // [16][128]
                       const float* __restrict__ wfc0,  // [128][32]
                       float* __restrict__ wtc,         // [81][16]
                       float* __restrict__ wt1,         // [128][16]
                       short* __restrict__ bfrag)       // [8][64][8] bf16
{
    int tid = threadIdx.x;
    for (int i = tid; i < KSn * KSn * Cn; i += 256) {
        int t = i / Cn, c = i - t * Cn;
        wtc[i] = wp[c * (KSn * KSn) + t];
    }
    for (int i = tid; i < HIDn * Cn; i += 256) {
        int o = i / Cn, c = i - o * Cn;
        wt1[i] = wfc1[c * HIDn + o];
    }
    for (int i = tid; i < 8 * 64 * 8; i += 256) {
        int nt = i >> 9;
        int rem = i & 511;
        int l = rem >> 3, j = rem & 7;
        int n = nt * 16 + (l & 15);
        int k = (l >> 4) * 8 + j;
        bfrag[i] = f2bf(wfc0[n * 32 + k]);
    }
}

#define FMA4(A, Q, V) \
    A.x = fmaf(Q.x, V.x, A.x); A.y = fmaf(Q.y, V.y, A.y); \
    A.z = fmaf(Q.z, V.z, A.z); A.w = fmaf(Q.w, V.w, A.w);

// ---------------------------------------------------------------------------
// Fused: LDS-staged depthwise 9x9 reflect conv + fc0 MFMA + bf16 h store +
// per-block BN partial stats.
// ---------------------------------------------------------------------------
__global__ __launch_bounds__(256) void k_fused(
    const float* __restrict__ xin,    // [B][H][W][16]
    const float* __restrict__ wtc,    // [81][16]
    const float* __restrict__ bp,     // [16]
    const short* __restrict__ bfrag,  // [8][64][8]
    const float* __restrict__ bfc0,   // [128]
    unsigned short* __restrict__ hbf, // [B][128][HW] bf16
    float2* __restrict__ part)        // [128][CBLK]
{
    __shared__ __align__(16) char smraw[4 * SROWS * SCOLS * 16];  // 50688 B
    float4* stg = (float4*)smraw;                       // [4][11][72]
    float (*sdx)[33] = (float(*)[33])smraw;             // [192][33] (aliases)
    float2 (*psum)[HIDn] = (float2(*)[HIDn])(smraw + TPXc * 33 * 4);

    int tid  = threadIdx.x;
    int lane = tid & 63;
    int w    = __builtin_amdgcn_readfirstlane(tid >> 6);

    int blk = blockIdx.x;
    int b   = blk / TPIc;
    int t   = blk - b * TPIc;
    int ty  = t / 3;
    int tx  = t - ty * 3;
    int y0  = ty * VY;
    int x0  = tx * 64;

    // ---- stage x tile (own quad only -> no barrier needed) ----
    const float4* xb4 = (const float4*)(xin + (size_t)b * HWn * Cn);
    int rrow[SROWS];
#pragma unroll
    for (int ri = 0; ri < SROWS; ++ri)
        rrow[ri] = refl(y0 + ri - PADn, Hn) * (Wn * 4);

    float4* stw = stg + w * (SROWS * SCOLS);
#pragma unroll
    for (int it = 0; it < 13; ++it) {
        int e = it * 64 + lane;
        if (e < SROWS * SCOLS) {
            int ri  = e / SCOLS;
            int col = e - ri * SCOLS;
            int gc  = refl(x0 + col - PADn, Wn);
            stw[e] = xb4[rrow[ri] + gc * 4 + w];
        }
    }

    // ---- conv: 3 output rows, quad w, from LDS ----
    const float4* wt4 = (const float4*)wtc;             // [81][4]
    float4 bq = ((const float4*)bp)[w];
    float4 a0 = bq, a1 = bq, a2 = bq;
#pragma unroll
    for (int ri = 0; ri < SROWS; ++ri) {
#pragma unroll
        for (int dx = 0; dx < KSn; ++dx) {
            float4 v = stw[ri * SCOLS + lane + dx];
            if (ri <= 8)            { float4 q = wt4[(ri * KSn + dx) * 4 + w];        FMA4(a0, q, v); }
            if (ri >= 1 && ri <= 9) { float4 q = wt4[((ri - 1) * KSn + dx) * 4 + w];  FMA4(a1, q, v); }
            if (ri >= 2)            { float4 q = wt4[((ri - 2) * KSn + dx) * 4 + w];  FMA4(a2, q, v); }
        }
    }
    float4 cen0 = stw[4 * SCOLS + lane + 4];
    float4 cen1 = stw[5 * SCOLS + lane + 4];
    float4 cen2 = stw[6 * SCOLS + lane + 4];

    __syncthreads();   // all stg reads done before sdx overwrites the region

    // ---- write dxv (x-center ch 0-15, conv ch 16-31) to sdx ----
#pragma unroll
    for (int r = 0; r < VY; ++r) {
        int px = r * 64 + lane;
        float4 cv = r == 0 ? cen0 : (r == 1 ? cen1 : cen2);
        float4 av = r == 0 ? a0   : (r == 1 ? a1   : a2);
        sdx[px][4 * w + 0] = cv.x;  sdx[px][4 * w + 1] = cv.y;
        sdx[px][4 * w + 2] = cv.z;  sdx[px][4 * w + 3] = cv.w;
        sdx[px][Cn + 4 * w + 0] = av.x;  sdx[px][Cn + 4 * w + 1] = av.y;
        sdx[px][Cn + 4 * w + 2] = av.z;  sdx[px][Cn + 4 * w + 3] = av.w;
    }
    __syncthreads();

    // ---- fc0 MFMA: wave w owns px [48w, 48w+48) x 128 outputs ----
    int l15 = lane & 15;
    int kg  = lane >> 4;

    short8 A[3];
#pragma unroll
    for (int mt = 0; mt < 3; ++mt) {
        int px = 48 * w + mt * 16 + l15;
#pragma unroll
        for (int j = 0; j < 8; ++j)
            A[mt][j] = f2bf(sdx[px][kg * 8 + j]);
    }

    short8 Bf[8];
    const short8* bgp = (const short8*)bfrag;
#pragma unroll
    for (int nt = 0; nt < 8; ++nt) Bf[nt] = bgp[nt * 64 + lane];

#pragma unroll
    for (int nt = 0; nt < 8; ++nt) {
        int o = nt * 16 + l15;
        float bn = bfc0[o];
        float s = 0.f, q = 0.f;
#pragma unroll
        for (int mt = 0; mt < 3; ++mt) {
            f32x4 c = {bn, bn, bn, bn};
            c = __builtin_amdgcn_mfma_f32_16x16x32_bf16(A[mt], Bf[nt], c, 0, 0, 0);
            // stats on fp32 accumulators
            s += c[0] + c[1] + c[2] + c[3];
            q += c[0]*c[0] + c[1]*c[1] + c[2]*c[2] + c[3]*c[3];
            // pack to bf16 and store
            unsigned lo = (f2bfu(c[1]) << 16) | f2bfu(c[0]);
            unsigned hi = (f2bfu(c[3]) << 16) | f2bfu(c[2]);
            int pxb = 48 * w + 16 * mt + 4 * kg;
            int p   = (y0 + (pxb >> 6)) * Wn + x0 + (pxb & 63);
            *(uint2*)(hbf + (size_t)(b * HIDn + o) * HWn + p) = make_uint2(lo, hi);
        }
        s += __shfl_xor(s, 16, 64);  q += __shfl_xor(q, 16, 64);
        s += __shfl_xor(s, 32, 64);  q += __shfl_xor(q, 32, 64);
        if (kg == 0) psum[w][o] = make_float2(s, q);
    }
    __syncthreads();

    if (tid < HIDn) {
        float2 p0 = psum[0][tid], p1 = psum[1][tid];
        float2 p2 = psum[2][tid], p3 = psum[3][tid];
        part[(size_t)tid * CBLK + blk] =
            make_float2(p0.x + p1.x + p2.x + p3.x, p0.y + p1.y + p2.y + p3.y);
    }
}

// ---------------------------------------------------------------------------
// Combine partials -> scale/shift per channel.
// ---------------------------------------------------------------------------
__global__ __launch_bounds__(256) void k_combine(
    const float2* __restrict__ part,  // [128][CBLK]
    const float* __restrict__ gamma,
    const float* __restrict__ beta,
    float2* __restrict__ scsh)        // [128]
{
    int o   = blockIdx.x;
    int tid = threadIdx.x;
    float s = 0.f, q = 0.f;
    for (int i = tid; i < CBLK; i += 256) {
        float2 v = part[(size_t)o * CBLK + i];
        s += v.x; q += v.y;
    }
#pragma unroll
    for (int off = 32; off > 0; off >>= 1) {
        s += __shfl_xor(s, off, 64);
        q += __shfl_xor(q, off, 64);
    }
    __shared__ float rs[4], rq[4];
    int wv = tid >> 6;
    if ((tid & 63) == 0) { rs[wv] = s; rq[wv] = q; }
    __syncthreads();
    if (tid == 0) {
        float S = rs[0] + rs[1] + rs[2] + rs[3];
        float Q = rq[0] + rq[1] + rq[2] + rq[3];
        float mean = S * (1.0f / BHWn);
        float var  = Q * (1.0f / BHWn) - mean * mean;
        float g    = gamma[o] * rsqrtf(var + EPSf);
        scsh[o] = make_float2(g, beta[o] - mean * g);
    }
}

// ---------------------------------------------------------------------------
// Update: BN + ReLU + fc1 + masked x update (h now bf16, scsh direct).
// ---------------------------------------------------------------------------
__global__ __launch_bounds__(256) void k_update(
    const float* __restrict__ xin,            // [B][H][W][16]
    const unsigned short* __restrict__ hbf,   // [B][128][HW] bf16
    const float2* __restrict__ scsh,          // [128]
    const float* __restrict__ wt1,            // [128][16]
    const float* __restrict__ u,              // [B][HW]
    float* __restrict__ xout)                 // [B][H][W][16]
{
    __shared__ float pacc[4][64][17];

    int tid  = threadIdx.x;
    int lane = tid & 63;
    int w    = __builtin_amdgcn_readfirstlane(tid >> 6);

    int blk = blockIdx.x;
    int b   = blk / (HWn / 64);
    int pb  = (blk - b * (HWn / 64)) * 64;
    int p   = pb + lane;

    const unsigned short* hsrc = hbf + (size_t)b * HIDn * HWn + p;

    float acc[Cn];
#pragma unroll
    for (int c = 0; c < Cn; ++c) acc[c] = 0.f;

#pragma unroll 4
    for (int j = 0; j < 32; ++j) {
        int o = w * 32 + j;                       // wave-uniform
        float2 g = scsh[o];                       // s_load
        float hv = bf2f(hsrc[(size_t)o * HWn]);
        float hn = fmaxf(fmaf(hv, g.x, g.y), 0.f);
        const float* wr = wt1 + o * Cn;           // s_load
#pragma unroll
        for (int c = 0; c < Cn; ++c) acc[c] = fmaf(wr[c], hn, acc[c]);
    }

#pragma unroll
    for (int c = 0; c < Cn; ++c) pacc[w][lane][c] = acc[c];
    __syncthreads();

    float4 r = make_float4(0.f, 0.f, 0.f, 0.f);
#pragma unroll
    for (int w2 = 0; w2 < 4; ++w2) {
        r.x += pacc[w2][lane][4 * w + 0];
        r.y += pacc[w2][lane][4 * w + 1];
        r.z += pacc[w2][lane][4 * w + 2];
        r.w += pacc[w2][lane][4 * w + 3];
    }
    if (w == 0) r.x = 0.f;                        // channel 0 frozen

    float m = u[(size_t)b * HWn + p] > FIREf ? 1.f : 0.f;
    size_t xoff = ((size_t)b * HWn + p) * Cn + 4 * w;
    float4 xv = *(const float4*)(xin + xoff);
    xv.x = fmaf(r.x, m, xv.x);
    xv.y = fmaf(r.y, m, xv.y);
    xv.z = fmaf(r.z, m, xv.z);
    xv.w = fmaf(r.w, m, xv.w);
    *(float4*)(xout + xoff) = xv;
}

// ---------------------------------------------------------------------------
extern "C" void kernel_launch(void* const* d_in, const int* in_sizes, int n_in,
                              void* d_out, int out_size, void* d_ws, size_t ws_size,
                              hipStream_t stream) {
    const float* x0   = (const float*)d_in[0];
    const float* ru   = (const float*)d_in[1];
    const float* wp   = (const float*)d_in[2];
    const float* bp   = (const float*)d_in[3];
    const float* wfc0 = (const float*)d_in[4];
    const float* bfc0 = (const float*)d_in[5];
    const float* wfc1 = (const float*)d_in[6];
    const float* gm   = (const float*)d_in[7];
    const float* bt   = (const float*)d_in[8];

    float* ws = (float*)d_ws;
    unsigned short* hbf = (unsigned short*)ws;            // 18,874,368 u16 = 9,437,184 f
    float* xbuf  = ws + 9437184;                          // 2,359,296 f
    float* wtc   = xbuf + 2359296;                        // 1312 f
    float* wt1   = wtc + 1312;                            // 2048 f
    short* bfrag = (short*)(wt1 + 2048);                  // 4096 s = 2048 f
    float2* part = (float2*)(wt1 + 2048 + 2048);          // 128*768 f2 = 196608 f
    float2* scsh = part + (size_t)HIDn * CBLK;            // 128 f2

    k_prep<<<1, 256, 0, stream>>>(wp, wfc1, wfc0, wtc, wt1, bfrag);

    const float* xcur = x0;
    for (int s = 0; s < STEPSn; ++s) {
        k_fused<<<CBLK, 256, 0, stream>>>(xcur, wtc, bp, bfrag, bfc0, hbf, part);
        k_combine<<<HIDn, 256, 0, stream>>>(part, gm, bt, scsh);
        float* xo = (s == STEPSn - 1) ? (float*)d_out : xbuf;
        k_update<<<BHWn / 64, 256, 0, stream>>>(xcur, hbf, scsh, wt1,
                                                ru + (size_t)s * BHWn, xo);
        xcur = xo;
    }
}